// Round 3
// baseline (9156.426 us; speedup 1.0000x reference)
//
#include <hip/hip_runtime.h>
#include <math.h>

#define Bsz 16
#define Tsz 1000
#define Nsz 100
#define ENC 512
#define VOCAB 10025
#define EMB 640
#define HID 1024
#define ATT 1024
#define KX (EMB + ENC)          // 1152
#define KRO (HID + EMB + ENC)   // 2176
#define G4 (4 * HID)            // 4096

typedef short s16x8 __attribute__((ext_vector_type(8)));
typedef unsigned short u16x4 __attribute__((ext_vector_type(4)));
typedef unsigned short u16x8 __attribute__((ext_vector_type(8)));
typedef float f32x4 __attribute__((ext_vector_type(4)));

__device__ __forceinline__ float4 ld4(const float* p) { return *reinterpret_cast<const float4*>(p); }
__device__ __forceinline__ float dot4(float4 a, float4 b) { return a.x*b.x + a.y*b.y + a.z*b.z + a.w*b.w; }
__device__ __forceinline__ float sigmoidf_(float x) { return 1.f / (1.f + __expf(-x)); }
__device__ __forceinline__ float ftanh_(float x) {
    x = fminf(15.f, fmaxf(-15.f, x));
    float e = __expf(2.f * x);
    return (e - 1.f) / (e + 1.f);
}
__device__ __forceinline__ unsigned short f2bf(float x) {
    union { float f; unsigned u; } v; v.f = x;
    unsigned r = v.u + 0x7fffu + ((v.u >> 16) & 1u);
    return (unsigned short)(r >> 16);
}
__device__ __forceinline__ float bf2f(unsigned short h) {
    union { float f; unsigned u; } v; v.u = ((unsigned)h) << 16;
    return v.f;
}

// ---------------- init: zero accum + bias sum ----------------
__global__ __launch_bounds__(256) void k_init(float* accum, const float* __restrict__ bih,
                                              const float* __restrict__ bhh, float* __restrict__ bsum) {
    int i = blockIdx.x * 256 + threadIdx.x;
    if (i < Bsz * Tsz) accum[i] = 0.f;
    if (i < G4) bsum[i] = bih[i] + bhh[i];
}

// ---------------- shifted embedding into roA[:, HID:HID+EMB] ----------------
__global__ __launch_bounds__(256) void k_embed(const int* __restrict__ labels,
                                               const float* __restrict__ table,
                                               float* __restrict__ roA) {
    int idx = blockIdx.x * 256 + threadIdx.x;
    if (idx >= Bsz * Nsz * EMB) return;
    int e = idx % EMB;
    int bn = idx / EMB;
    int n = bn % Nsz, b = bn / Nsz;
    float v = 0.f;
    if (n > 0) {
        int lab = labels[b * Nsz + n - 1];
        v = table[(size_t)lab * EMB + e];
    }
    roA[(size_t)bn * KRO + HID + e] = v;
}

// ======== MFMA split-bf16 GEMM: C = A[M,K](lda) @ W[Nc,K](ldw)^T + bias ========
// MODE 0: fp32 out. MODE 1: maxout pairs fp32 out. MODE 2: bf16 out.
template <int MODE>
__global__ __launch_bounds__(256) void mfma_gemm(const float* __restrict__ A, int lda,
                                                 const float* __restrict__ W, int ldw,
                                                 const float* __restrict__ bias,
                                                 float* __restrict__ C,
                                                 int M, int Nc, int K, int ldC) {
    __shared__ unsigned short Ah[128][40], Al[128][40], Wh[128][40], Wl[128][40];
    int tid = threadIdx.x;
    int lane = tid & 63;
    int wave = tid >> 6;
    int wm = (wave >> 1) * 64, wn = (wave & 1) * 64;
    int m0 = blockIdx.y * 128, n0 = blockIdx.x * 128;
    int lrow = tid >> 1;
    int lcol = (tid & 1) * 16;
    bool aval = (m0 + lrow) < M;
    bool wval = (n0 + lrow) < Nc;
    const float* Arow = A + (size_t)(m0 + lrow) * lda + lcol;
    const float* Wrow = W + (size_t)(n0 + lrow) * ldw + lcol;
    int frow = lane & 15, fk = (lane >> 4) * 8;

    f32x4 acc[4][4];
#pragma unroll
    for (int i = 0; i < 4; i++)
#pragma unroll
        for (int j = 0; j < 4; j++) acc[i][j] = (f32x4){0.f, 0.f, 0.f, 0.f};

    const float4 z4 = {0.f, 0.f, 0.f, 0.f};
    for (int k0 = 0; k0 < K; k0 += 32) {
#pragma unroll
        for (int c = 0; c < 16; c += 4) {
            float4 av = aval ? ld4(Arow + k0 + c) : z4;
            u16x4 hv, lv;
            hv.x = f2bf(av.x); lv.x = f2bf(av.x - bf2f(hv.x));
            hv.y = f2bf(av.y); lv.y = f2bf(av.y - bf2f(hv.y));
            hv.z = f2bf(av.z); lv.z = f2bf(av.z - bf2f(hv.z));
            hv.w = f2bf(av.w); lv.w = f2bf(av.w - bf2f(hv.w));
            *(u16x4*)&Ah[lrow][lcol + c] = hv;
            *(u16x4*)&Al[lrow][lcol + c] = lv;
            float4 wv = wval ? ld4(Wrow + k0 + c) : z4;
            hv.x = f2bf(wv.x); lv.x = f2bf(wv.x - bf2f(hv.x));
            hv.y = f2bf(wv.y); lv.y = f2bf(wv.y - bf2f(hv.y));
            hv.z = f2bf(wv.z); lv.z = f2bf(wv.z - bf2f(hv.z));
            hv.w = f2bf(wv.w); lv.w = f2bf(wv.w - bf2f(hv.w));
            *(u16x4*)&Wh[lrow][lcol + c] = hv;
            *(u16x4*)&Wl[lrow][lcol + c] = lv;
        }
        __syncthreads();
        s16x8 afh[4], afl[4], bfh[4], bfl[4];
#pragma unroll
        for (int i = 0; i < 4; i++) {
            afh[i] = *(const s16x8*)&Ah[wm + i * 16 + frow][fk];
            afl[i] = *(const s16x8*)&Al[wm + i * 16 + frow][fk];
            bfh[i] = *(const s16x8*)&Wh[wn + i * 16 + frow][fk];
            bfl[i] = *(const s16x8*)&Wl[wn + i * 16 + frow][fk];
        }
#pragma unroll
        for (int mi = 0; mi < 4; mi++)
#pragma unroll
            for (int ni = 0; ni < 4; ni++) {
                acc[mi][ni] = __builtin_amdgcn_mfma_f32_16x16x32_bf16(afh[mi], bfh[ni], acc[mi][ni], 0, 0, 0);
                acc[mi][ni] = __builtin_amdgcn_mfma_f32_16x16x32_bf16(afl[mi], bfh[ni], acc[mi][ni], 0, 0, 0);
                acc[mi][ni] = __builtin_amdgcn_mfma_f32_16x16x32_bf16(afh[mi], bfl[ni], acc[mi][ni], 0, 0, 0);
            }
        __syncthreads();
    }
    int crb = (lane >> 4) * 4;
    int ccol = lane & 15;
#pragma unroll
    for (int mi = 0; mi < 4; mi++) {
#pragma unroll
        for (int r = 0; r < 4; r++) {
            int m = m0 + wm + mi * 16 + crb + r;
#pragma unroll
            for (int ni = 0; ni < 4; ni++) {
                int n = n0 + wn + ni * 16 + ccol;
                if (MODE == 0) {
                    if (m < M && n < Nc) C[(size_t)m * ldC + n] = acc[mi][ni][r] + bias[n];
                } else if (MODE == 2) {
                    if (m < M && n < Nc)
                        ((unsigned short*)C)[(size_t)m * ldC + n] = f2bf(acc[mi][ni][r] + bias[n]);
                } else {
                    float v = (n < Nc) ? acc[mi][ni][r] + bias[n] : -INFINITY;
                    float o = __shfl_xor(v, 1, 64);
                    if (((lane & 1) == 0) && m < M && n < Nc)
                        C[(size_t)m * ldC + (n >> 1)] = fmaxf(v, o);
                }
            }
        }
    }
}

// ---------------- inv_fertility ----------------
__global__ __launch_bounds__(256) void k_ifert(const float* __restrict__ enc,
                                               const float* __restrict__ Wfert,
                                               float* __restrict__ ifert) {
    int wv = (blockIdx.x * 256 + threadIdx.x) >> 6;
    int lane = threadIdx.x & 63;
    if (wv >= Bsz * Tsz) return;
    const float* row = enc + (size_t)wv * ENC;
    float s = 0.f;
    for (int k = lane * 4; k < ENC; k += 256) s += dot4(ld4(row + k), ld4(Wfert + k));
    for (int o = 32; o; o >>= 1) s += __shfl_xor(s, o, 64);
    if (lane == 0) ifert[wv] = 1.f / (1.f + __expf(-s));
}

// ---------------- gates v2: one wave per hidden unit j, all 16 batches ----------------
__global__ __launch_bounds__(256) void k_gates2(float* __restrict__ roA, float* __restrict__ cbuf,
                                                const float* __restrict__ gpre,
                                                const float* __restrict__ Wih, const float* __restrict__ Whh,
                                                int t) {
    __shared__ float red[4][4][16];
    int lane = threadIdx.x & 63;
    int wid = threadIdx.x >> 6;
    int j = blockIdx.x * 4 + wid;  // 0..1023
    float acc[4][16];
#pragma unroll
    for (int g = 0; g < 4; g++)
#pragma unroll
        for (int b = 0; b < 16; b++) acc[g][b] = 0.f;
    if (t > 0) {
        const float* wc0 = Wih + (size_t)(0 * HID + j) * KX + EMB;
        const float* wc1 = Wih + (size_t)(1 * HID + j) * KX + EMB;
        const float* wc2 = Wih + (size_t)(2 * HID + j) * KX + EMB;
        const float* wc3 = Wih + (size_t)(3 * HID + j) * KX + EMB;
        const float* wh0 = Whh + (size_t)(0 * HID + j) * HID;
        const float* wh1 = Whh + (size_t)(1 * HID + j) * HID;
        const float* wh2 = Whh + (size_t)(2 * HID + j) * HID;
        const float* wh3 = Whh + (size_t)(3 * HID + j) * HID;
        for (int k = lane * 4; k < ENC; k += 256) {
            float4 w0 = ld4(wc0 + k), w1 = ld4(wc1 + k), w2 = ld4(wc2 + k), w3 = ld4(wc3 + k);
#pragma unroll
            for (int b = 0; b < 16; b++) {
                float4 x = ld4(&roA[(size_t)(b * Nsz + t - 1) * KRO + HID + EMB + k]);
                acc[0][b] += dot4(w0, x); acc[1][b] += dot4(w1, x);
                acc[2][b] += dot4(w2, x); acc[3][b] += dot4(w3, x);
            }
        }
        for (int k = lane * 4; k < HID; k += 256) {
            float4 w0 = ld4(wh0 + k), w1 = ld4(wh1 + k), w2 = ld4(wh2 + k), w3 = ld4(wh3 + k);
#pragma unroll
            for (int b = 0; b < 16; b++) {
                float4 x = ld4(&roA[(size_t)(b * Nsz + t - 1) * KRO + k]);
                acc[0][b] += dot4(w0, x); acc[1][b] += dot4(w1, x);
                acc[2][b] += dot4(w2, x); acc[3][b] += dot4(w3, x);
            }
        }
    }
#pragma unroll
    for (int g = 0; g < 4; g++)
#pragma unroll
        for (int b = 0; b < 16; b++) {
            float v = acc[g][b];
            for (int o = 32; o; o >>= 1) v += __shfl_xor(v, o, 64);
            if (lane == 0) red[wid][g][b] = v;
        }
    __syncthreads();
    if (lane < 16) {
        int b = lane;
        const float* gp = gpre + (size_t)(b * Nsz + t) * G4 + j;
        float gi = red[wid][0][b] + gp[0];
        float gf = red[wid][1][b] + gp[HID];
        float gg = red[wid][2][b] + gp[2 * HID];
        float go = red[wid][3][b] + gp[3 * HID];
        float cold = (t > 0) ? cbuf[b * HID + j] : 0.f;
        float cn = sigmoidf_(gf) * cold + sigmoidf_(gi) * ftanh_(gg);
        float hn = sigmoidf_(go) * ftanh_(cn);
        cbuf[b * HID + j] = cn;
        roA[(size_t)(b * Nsz + t) * KRO + j] = hn;
    }
}

// ---------------- s_t = h_new @ W_s^T ----------------
__global__ __launch_bounds__(256) void k_s(const float* __restrict__ roA, const float* __restrict__ Wsm,
                                           float* __restrict__ st, int t) {
    int wv = (blockIdx.x * 256 + threadIdx.x) >> 6;
    int lane = threadIdx.x & 63;
    float acc[16];
#pragma unroll
    for (int b = 0; b < 16; b++) acc[b] = 0.f;
    const float* wr = Wsm + (size_t)wv * HID;
    for (int k = lane * 4; k < HID; k += 256) {
        float4 w = ld4(wr + k);
#pragma unroll
        for (int b = 0; b < 16; b++) acc[b] += dot4(w, ld4(&roA[(size_t)(b * Nsz + t) * KRO + k]));
    }
#pragma unroll
    for (int b = 0; b < 16; b++) {
        float v = acc[b];
        for (int o = 32; o; o >>= 1) v += __shfl_xor(v, o, 64);
        acc[b] = v;
    }
    if (lane < 16) st[lane * ATT + wv] = acc[lane];
}

// ---------------- energies (bf16 enc_ctx) + ctx-slot zeroing ----------------
__global__ __launch_bounds__(256) void k_energy(const unsigned short* __restrict__ encctx,
                                                const float* __restrict__ st,
                                                const float* __restrict__ Wfb,
                                                const float* __restrict__ vatt,
                                                const float* __restrict__ accum,
                                                const int* __restrict__ seqlen,
                                                float* __restrict__ enw,
                                                float* __restrict__ roA, int tstep) {
    if (blockIdx.x < Bsz) {  // zero ctx slot for batch blockIdx.x (before softctx atomics)
        float* dst = roA + (size_t)(blockIdx.x * Nsz + tstep) * KRO + HID + EMB;
        dst[threadIdx.x] = 0.f;
        dst[threadIdx.x + 256] = 0.f;
    }
    int wv = (blockIdx.x * 256 + threadIdx.x) >> 6;
    int lane = threadIdx.x & 63;
    int b = wv / Tsz, t = wv - b * Tsz;
    if (t >= seqlen[b]) {
        if (lane == 0) enw[wv] = -INFINITY;
        return;
    }
    float ac = accum[wv];
    const unsigned short* ec = encctx + (size_t)wv * ATT;
    const float* sr = st + b * ATT;
    float e = 0.f;
    for (int k = lane * 8; k < ATT; k += 512) {
        u16x8 c8 = *(const u16x8*)(ec + k);
        float4 sa = ld4(sr + k), sb = ld4(sr + k + 4);
        float4 fa = ld4(Wfb + k), fb = ld4(Wfb + k + 4);
        float4 va = ld4(vatt + k), vb = ld4(vatt + k + 4);
        e += ftanh_(bf2f(c8[0]) + sa.x + ac * fa.x) * va.x;
        e += ftanh_(bf2f(c8[1]) + sa.y + ac * fa.y) * va.y;
        e += ftanh_(bf2f(c8[2]) + sa.z + ac * fa.z) * va.z;
        e += ftanh_(bf2f(c8[3]) + sa.w + ac * fa.w) * va.w;
        e += ftanh_(bf2f(c8[4]) + sb.x + ac * fb.x) * vb.x;
        e += ftanh_(bf2f(c8[5]) + sb.y + ac * fb.y) * vb.y;
        e += ftanh_(bf2f(c8[6]) + sb.z + ac * fb.z) * vb.z;
        e += ftanh_(bf2f(c8[7]) + sb.w + ac * fb.w) * vb.w;
    }
    for (int o = 32; o; o >>= 1) e += __shfl_xor(e, o, 64);
    if (lane == 0) enw[wv] = e;
}

// ---------------- fused softmax + accum + context ----------------
#define TCH 10
__global__ __launch_bounds__(256) void k_softctx(const float* __restrict__ enw,
                                                 const float* __restrict__ ifert,
                                                 float* __restrict__ accum,
                                                 const float* __restrict__ enc,
                                                 const int* __restrict__ seqlen,
                                                 float* __restrict__ roA, int tstep) {
    int b = blockIdx.y, tid = threadIdx.x;
    __shared__ float redm[4], reds[4];
    int len = seqlen[b];
    const float* row = enw + b * Tsz;
    float m = -INFINITY;
    for (int i = tid; i < len; i += 256) m = fmaxf(m, row[i]);
    for (int o = 32; o; o >>= 1) m = fmaxf(m, __shfl_xor(m, o, 64));
    if ((tid & 63) == 0) redm[tid >> 6] = m;
    __syncthreads();
    float M = fmaxf(fmaxf(redm[0], redm[1]), fmaxf(redm[2], redm[3]));
    float s = 0.f;
    for (int i = tid; i < len; i += 256) s += __expf(row[i] - M);
    for (int o = 32; o; o >>= 1) s += __shfl_xor(s, o, 64);
    if ((tid & 63) == 0) reds[tid >> 6] = s;
    __syncthreads();
    float inv = 1.f / (reds[0] + reds[1] + reds[2] + reds[3]);
    int t0 = blockIdx.x * (Tsz / TCH);
    int t1 = min(t0 + Tsz / TCH, len);
    for (int i = t0 + tid; i < t1; i += 256)
        accum[b * Tsz + i] += __expf(row[i] - M) * inv * ifert[b * Tsz + i] * 0.5f;
    if (t0 >= t1) return;
    float a0 = 0.f, a1 = 0.f;
    for (int i = t0; i < t1; i++) {
        float w = __expf(row[i] - M) * inv;
        const float* er = enc + (size_t)(b * Tsz + i) * ENC;
        a0 += w * er[tid];
        a1 += w * er[tid + 256];
    }
    float* dst = roA + (size_t)(b * Nsz + tstep) * KRO + HID + EMB;
    atomicAdd(dst + tid, a0);
    atomicAdd(dst + tid + 256, a1);
}

// ---------------- final small outputs ----------------
__global__ __launch_bounds__(256) void k_final(const float* __restrict__ roA, const float* __restrict__ cbuf,
                                               const float* __restrict__ accum, float* __restrict__ out) {
    int idx = blockIdx.x * 256 + threadIdx.x;
    const int base = Bsz * Nsz * VOCAB;
    const int OH = Bsz * HID, OC = Bsz * HID, OA = Bsz * ENC, OAC = Bsz * Tsz;
    if (idx < OH) {
        int b = idx / HID, j = idx % HID;
        out[base + idx] = roA[(size_t)(b * Nsz + Nsz - 1) * KRO + j];
        return;
    }
    idx -= OH;
    if (idx < OC) { out[base + OH + idx] = cbuf[idx]; return; }
    idx -= OC;
    if (idx < OA) {
        int b = idx / ENC, d = idx % ENC;
        out[base + OH + OC + idx] = roA[(size_t)(b * Nsz + Nsz - 1) * KRO + HID + EMB + d];
        return;
    }
    idx -= OA;
    if (idx < OAC) out[base + OH + OC + OA + idx] = accum[idx];
}

extern "C" void kernel_launch(void* const* d_in, const int* in_sizes, int n_in,
                              void* d_out, int out_size, void* d_ws, size_t ws_size,
                              hipStream_t stream) {
    const float* enc   = (const float*)d_in[0];
    const int* labels  = (const int*)d_in[1];
    const int* seqlen  = (const int*)d_in[2];
    const float* table = (const float*)d_in[3];
    const float* Wih   = (const float*)d_in[4];
    const float* Whh   = (const float*)d_in[5];
    const float* bih   = (const float*)d_in[6];
    const float* bhh   = (const float*)d_in[7];
    const float* Wsm   = (const float*)d_in[8];
    const float* Wenc  = (const float*)d_in[9];
    const float* benc  = (const float*)d_in[10];
    const float* vatt  = (const float*)d_in[11];
    const float* Wfert = (const float*)d_in[12];
    const float* Wfb   = (const float*)d_in[13];
    const float* Wro   = (const float*)d_in[14];
    const float* bro   = (const float*)d_in[15];
    const float* Wout  = (const float*)d_in[16];
    const float* bout  = (const float*)d_in[17];
    float* out = (float*)d_out;

    // workspace layout (floats); total ~19.1M floats = ~76.5 MB
    float* ws = (float*)d_ws;
    float* roA  = ws;                                 // [1600][KRO]
    float* cbuf = roA + (size_t)1600 * KRO;           // 16384
    float* gpre = cbuf + Bsz * HID;                   // [1600][4096]
    unsigned short* encctx = (unsigned short*)(gpre + (size_t)1600 * G4);  // [16000][1024] bf16
    float* after = gpre + (size_t)1600 * G4 + (size_t)Bsz * Tsz * ATT / 2;
    float* ifert = after;                             // 16000
    float* accum = ifert + Bsz * Tsz;                 // 16000
    float* enw   = accum + Bsz * Tsz;                 // 16000
    float* st    = enw + Bsz * Tsz;                   // 16384
    float* bsum  = st + Bsz * ATT;                    // 4096
    float* rmx   = bsum + G4;                         // [1600][512]

    k_init<<<(Bsz * Tsz + 255) / 256, 256, 0, stream>>>(accum, bih, bhh, bsum);
    k_embed<<<(Bsz * Nsz * EMB + 255) / 256, 256, 0, stream>>>(labels, table, roA);
    // gpre = emb @ W_ih[:, :EMB]^T + (b_ih + b_hh) : [1600,640]@[640,4096]
    mfma_gemm<0><<<dim3(G4 / 128, (1600 + 127) / 128), 256, 0, stream>>>(
        roA + HID, KRO, Wih, KX, bsum, gpre, 1600, G4, EMB, G4);
    // enc_ctx = enc @ W_enc^T + b_enc -> bf16 : [16000,512]@[512,1024]
    mfma_gemm<2><<<dim3(ATT / 128, (Bsz * Tsz) / 128), 256, 0, stream>>>(
        enc, ENC, Wenc, ENC, benc, (float*)encctx, Bsz * Tsz, ATT, ENC, ATT);
    k_ifert<<<(Bsz * Tsz * 64 + 255) / 256, 256, 0, stream>>>(enc, Wfert, ifert);

    for (int t = 0; t < Nsz; t++) {
        k_gates2<<<256, 256, 0, stream>>>(roA, cbuf, gpre, Wih, Whh, t);
        k_s<<<256, 256, 0, stream>>>(roA, Wsm, st, t);
        k_energy<<<(Bsz * Tsz * 64) / 256, 256, 0, stream>>>(encctx, st, Wfb, vatt, accum, seqlen,
                                                             enw, roA, t);
        k_softctx<<<dim3(TCH, Bsz), 256, 0, stream>>>(enw, ifert, accum, enc, seqlen, roA, t);
    }

    // readout: [1600,2176]@[2176,1024] + bias -> maxout -> rmx [1600,512]
    mfma_gemm<1><<<dim3(1024 / 128, (1600 + 127) / 128), 256, 0, stream>>>(
        roA, KRO, Wro, KRO, bro, rmx, 1600, 1024, KRO, 512);
    // logits: [1600,512]@[512,10025] + bias -> d_out
    mfma_gemm<0><<<dim3((VOCAB + 127) / 128, (1600 + 127) / 128), 256, 0, stream>>>(
        rmx, 512, Wout, 512, bout, out, 1600, VOCAB, 512, VOCAB);
    k_final<<<(Bsz * HID * 2 + Bsz * ENC + Bsz * Tsz + 255) / 256, 256, 0, stream>>>(roA, cbuf, accum, out);
}